// Round 8
// baseline (84.987 us; speedup 1.0000x reference)
//
#include <hip/hip_runtime.h>
#include <hip/hip_bf16.h>

typedef short bf16x8 __attribute__((ext_vector_type(8)));
typedef float f32x4 __attribute__((ext_vector_type(4)));
typedef unsigned short u16;

#define B_    32
#define L_    8192
#define C_    8
#define P_    512
#define D_    256
#define SED_  16
#define CED_  8
#define INDIM 2576
#define NROWS (B_ * P_)

#define TB_WTS 0
#define TB_IWT 1
#define TB_SYS 2
#define TB_GW1 3
#define TB_BWB 4
#define TB_CH0 5
#define TB_W2G 10
#define TB_B2  11

__device__ __forceinline__ u16 f2bf(float f) {
    __hip_bfloat16 h = __float2bfloat16(f);
    return *reinterpret_cast<u16*>(&h);
}

// ================================================================= zero tabF (replaces graph memset node)
__global__ __launch_bounds__(256) void k_zero(float* __restrict__ tabF) {
    tabF[blockIdx.x * 256 + threadIdx.x] = 0.f;
}

// ================================================================= prep (bit-identical to r7 — verified)
__global__ __launch_bounds__(256) void k_prep(
    const float* __restrict__ W1, const float* __restrict__ W2,
    const float* __restrict__ g1, const float* __restrict__ bb1,
    const float* __restrict__ g2, const float* __restrict__ bb2,
    const float* __restrict__ ce, const float* __restrict__ se,
    const int* __restrict__ ctm, const int* __restrict__ sysid,
    u16* __restrict__ wdt, u16* __restrict__ w2t,
    float* __restrict__ tabF, float* __restrict__ scal)
{
    __shared__ __attribute__((aligned(16))) char sh[8320];
    int c = blockIdx.x, n = threadIdx.x;

    if (c < 81) {
        float* sg = (float*)sh;
        float* sb = sg + 32;
        float* st = sb + 32;
        float (*cs5)[32] = (float(*)[32])(st + 32);
        int sid = sysid[0];
        int k0 = c * 32;
        int kend = INDIM - k0; if (kend > 32) kend = 32;
        int type = (k0 < 256) ? 0 : (k0 < 512) ? 1 : (k0 < 2560) ? 2 : 3;
        if (n < kend) {
            int k = k0 + n;
            sg[n] = g1[k]; sb[n] = bb1[k];
            float xv = 0.f;
            if (type == 1) xv = (float)((k - 256) >> 2);
            if (type == 3) xv = se[sid * SED_ + (k - 2560)];
            st[n] = xv;
        }
        if (type == 2 && n < 160) {
            int s = n >> 5, kt = n & 31, k = k0 + kt;
            cs5[s][kt] = ce[ctm[sid * 20 + s + ((k >> 3) & 3)] * CED_ + (k & 7)];
        }
        __syncthreads();
        float pg = 0, pb = 0, ai = 0, as_ = 0;
        float a5 = 0, a6 = 0, a7 = 0, a8 = 0, a9 = 0;
#pragma unroll 8
        for (int kt = 0; kt < kend; ++kt) {
            float wv = W1[(size_t)(k0 + kt) * D_ + n];
            float gw = sg[kt] * wv;
            pg += gw; pb += sb[kt] * wv;
            if (type == 1) ai += st[kt] * gw;
            if (type == 2) {
                a5 += cs5[0][kt] * gw; a6 += cs5[1][kt] * gw; a7 += cs5[2][kt] * gw;
                a8 += cs5[3][kt] * gw; a9 += cs5[4][kt] * gw;
            }
            if (type == 3) as_ += st[kt] * gw;
        }
        atomicAdd(&tabF[TB_GW1 * 256 + n], pg);
        atomicAdd(&tabF[TB_BWB * 256 + n], pb);
        if (type == 1) {
            atomicAdd(&tabF[TB_WTS * 256 + n], pg);
            atomicAdd(&tabF[TB_IWT * 256 + n], ai);
        }
        if (type == 2) {
            atomicAdd(&tabF[(TB_CH0 + 0) * 256 + n], a5);
            atomicAdd(&tabF[(TB_CH0 + 1) * 256 + n], a6);
            atomicAdd(&tabF[(TB_CH0 + 2) * 256 + n], a7);
            atomicAdd(&tabF[(TB_CH0 + 3) * 256 + n], a8);
            atomicAdd(&tabF[(TB_CH0 + 4) * 256 + n], a9);
        }
        if (type == 3) atomicAdd(&tabF[TB_SYS * 256 + n], as_);
    } else if (c < 89) {
        float* sg = (float*)sh;
        float* sb = sg + 32;
        int k0 = (c - 81) * 32;
        if (n < 32) { sg[n] = g2[k0 + n]; sb[n] = bb2[k0 + n]; }
        __syncthreads();
        float pg = 0, pb = 0;
#pragma unroll 8
        for (int kt = 0; kt < 32; ++kt) {
            float wv = W2[(size_t)(k0 + kt) * D_ + n];
            pg += sg[kt] * wv; pb += sb[kt] * wv;
        }
        atomicAdd(&tabF[TB_W2G * 256 + n], pg);
        atomicAdd(&tabF[TB_B2  * 256 + n], pb);
    } else if (c < 121) {
        u16 (*tileT)[65] = (u16(*)[65])sh;
        int trb = c - 89;
        const float* W = (trb < 16) ? W1 : W2;
        const float* g = (trb < 16) ? g1 : g2;
        u16* dst = (trb < 16) ? wdt : w2t;
        int bb = trb & 15;
        int tr = (bb >> 2) * 64;
        int tc = (bb & 3) * 64;
        int rr = n >> 2, cc = (n & 3) * 16;
        float gs = g[tr + rr];
        const float* src = W + (size_t)(tr + rr) * D_ + tc + cc;
#pragma unroll
        for (int j = 0; j < 16; ++j)
            tileT[cc + j][rr] = f2bf(gs * src[j]);
        __syncthreads();
        int nn = n >> 2, kb = (n & 3) * 16;
        u16* dp = dst + (size_t)(tc + nn) * 256 + tr + kb;
#pragma unroll
        for (int j = 0; j < 16; ++j)
            dp[j] = tileT[nn][kb + j];
    } else {
        float* sv = (float*)sh;
        float* sqv = sv + 176;
        int sid = sysid[0];
        if (n < 160) {
            int s5 = n >> 5, s = n & 31;
            float v = ce[ctm[sid * 20 + s5 + (s >> 3)] * CED_ + (s & 7)];
            sv[n] = v; sqv[n] = v * v;
        } else if (n < 176) {
            float v = se[sid * SED_ + (n - 160)];
            sv[n] = v; sqv[n] = v * v;
        }
        __syncthreads();
        if (n < 5) {
            float a = 0, bq = 0;
            for (int j2 = 0; j2 < 32; ++j2) { a += sv[n * 32 + j2]; bq += sqv[n * 32 + j2]; }
            scal[n] = a; scal[5 + n] = bq;
        }
        if (n == 10) {
            float a = 0, bq = 0;
            for (int j2 = 0; j2 < 16; ++j2) { a += sv[160 + j2]; bq += sqv[160 + j2]; }
            scal[10] = a; scal[11] = bq;
        }
        if (n >= 12 && n < 16) scal[n] = 0.f;
    }
}

// ================================================================= main fused (bit-identical to r7)
__global__ __launch_bounds__(512, 4) void k_main(
    const float* __restrict__ x, const float* __restrict__ fs,
    const int* __restrict__ sLp, const int* __restrict__ sCp,
    const u16* __restrict__ wdt, const u16* __restrict__ w2t,
    const float* __restrict__ tabF, const float* __restrict__ scal,
    const float* __restrict__ b1, const float* __restrict__ b2,
    float* __restrict__ out)
{
    __shared__ __attribute__((aligned(16))) u16 As[8 * 32 * 40];
    __shared__ __attribute__((aligned(16))) u16 Hs[8 * 32 * 40];
    __shared__ float tb[12 * 256];
    __shared__ __attribute__((aligned(16))) float ps1[32 * 8], ps2[32 * 8];
    __shared__ float rmu[32], rrs[32], rsl[32];
    __shared__ int   rsc[32];
    __shared__ float rmu2[32], rrs2[32];

    int t = threadIdx.x;
    int tile = ((blockIdx.x & 7) << 6) + (blockIdx.x >> 3);   // XCD-bijective
    int r0 = tile * 32;
    int b = r0 >> 9;
    float fsinv = 1.0f / fs[b];

    int row = t >> 4, u = t & 15;
    int w = t >> 6, lane = t & 63, l15 = lane & 15, hi = lane >> 4;
    int col0 = w * 32;

    int r = r0 + row;
    int sL = sLp[r], sC = sCp[r];

    // GEMM1 B-operand preload (lands under gather latency)
    bf16x8 bA[8], bB[8];
    {
        const u16* bp0 = &wdt[(col0 + l15) * 256 + hi * 8];
        const u16* bp1 = &wdt[(col0 + 16 + l15) * 256 + hi * 8];
#pragma unroll
        for (int kk = 0; kk < 8; ++kk) {
            bA[kk] = *(const bf16x8*)(bp0 + kk * 32);
            bB[kk] = *(const bf16x8*)(bp1 + kk * 32);
        }
    }

    for (int i = t; i < 12 * 256; i += 512) tb[i] = tabF[i];
    if (t < 256) tb[TB_BWB * 256 + t] += b1[t];
    else         tb[TB_B2  * 256 + (t - 256)] += b2[t - 256];

    // gather + LN1 stats
    {
        const float* xb = x + ((size_t)b << 16);
        float s = 0.f, sq = 0.f;
#pragma unroll
        for (int i2 = 0; i2 < 4; ++i2) {
            int i = i2 * 16 + u;
            const float* px = xb + (size_t)(sL + i) * 8 + sC;
            f32x4 v;
            __builtin_memcpy(&v, px, 16);
            s += v[0] + v[1] + v[2] + v[3];
            sq += v[0] * v[0] + v[1] * v[1] + v[2] * v[2] + v[3] * v[3];
            *(ushort4*)&As[(i2 * 2 + (u >> 3)) * 1280 + row * 40 + (u & 7) * 4] =
                make_ushort4(f2bf(v[0]), f2bf(v[1]), f2bf(v[2]), f2bf(v[3]));
        }
        s += __shfl_xor(s, 1); s += __shfl_xor(s, 2); s += __shfl_xor(s, 4); s += __shfl_xor(s, 8);
        sq += __shfl_xor(sq, 1); sq += __shfl_xor(sq, 2); sq += __shfl_xor(sq, 4); sq += __shfl_xor(sq, 8);
        if (u == 0) {
            float sLf = (float)sL;
            float Ss = s + 4.f * fsinv * (64.f * sLf + 2016.f) + 64.f * scal[sC] + scal[10];
            float Sq = sq + 4.f * fsinv * fsinv * (64.f * sLf * sLf + 4032.f * sLf + 85344.f)
                     + 64.f * scal[5 + sC] + scal[11];
            float mu = Ss * (1.f / (float)INDIM);
            float var = Sq * (1.f / (float)INDIM) - mu * mu;
            rmu[row] = mu; rrs[row] = rsqrtf(var + 1e-5f);
            rsl[row] = sLf; rsc[row] = sC;
        }
    }
    __syncthreads();                                           // B1

    // GEMM1
    f32x4 acc[2][2];
#pragma unroll
    for (int fm = 0; fm < 2; ++fm)
#pragma unroll
        for (int fn = 0; fn < 2; ++fn) acc[fm][fn] = (f32x4){0.f, 0.f, 0.f, 0.f};
#pragma unroll
    for (int kk = 0; kk < 8; ++kk) {
        bf16x8 a0 = *(const bf16x8*)&As[kk * 1280 + l15 * 40 + hi * 8];
        bf16x8 a1 = *(const bf16x8*)&As[kk * 1280 + (16 + l15) * 40 + hi * 8];
        acc[0][0] = __builtin_amdgcn_mfma_f32_16x16x32_bf16(a0, bA[kk], acc[0][0], 0, 0, 0);
        acc[1][0] = __builtin_amdgcn_mfma_f32_16x16x32_bf16(a1, bA[kk], acc[1][0], 0, 0, 0);
        acc[0][1] = __builtin_amdgcn_mfma_f32_16x16x32_bf16(a0, bB[kk], acc[0][1], 0, 0, 0);
        acc[1][1] = __builtin_amdgcn_mfma_f32_16x16x32_bf16(a1, bB[kk], acc[1][1], 0, 0, 0);
    }

    // GEMM2 B-operand preload (lands under epilogue-1)
    {
        const u16* bp0 = &w2t[(col0 + l15) * 256 + hi * 8];
        const u16* bp1 = &w2t[(col0 + 16 + l15) * 256 + hi * 8];
#pragma unroll
        for (int kk = 0; kk < 8; ++kk) {
            bA[kk] = *(const bf16x8*)(bp0 + kk * 32);
            bB[kk] = *(const bf16x8*)(bp1 + kk * 32);
        }
    }

    // epilogue1: LN1-fold + SiLU -> Hs, LN2 partial stats
    {
        float p_s[2][4] = {}, p_q[2][4] = {};
#pragma unroll
        for (int fn = 0; fn < 2; ++fn) {
            int colf = col0 + fn * 16 + l15;
            float vwts = tb[TB_WTS * 256 + colf];
            float viwt = tb[TB_IWT * 256 + colf];
            float vsys = tb[TB_SYS * 256 + colf];
            float vgw1 = tb[TB_GW1 * 256 + colf];
            float vbwb = tb[TB_BWB * 256 + colf];
            const float* tch = &tb[TB_CH0 * 256 + colf];
#pragma unroll
            for (int fm = 0; fm < 2; ++fm)
#pragma unroll
                for (int j = 0; j < 4; ++j) {
                    int rr = fm * 16 + hi * 4 + j;
                    float fw = acc[fm][fn][j]
                             + fsinv * (rsl[rr] * vwts + viwt)
                             + tch[rsc[rr] * 256] + vsys;
                    float o1 = rrs[rr] * (fw - rmu[rr] * vgw1) + vbwb;
                    float h = o1 / (1.f + __expf(-o1));
                    p_s[fm][j] += h; p_q[fm][j] += h * h;
                    Hs[w * 1280 + rr * 40 + fn * 16 + l15] = f2bf(h);
                }
        }
#pragma unroll
        for (int fm = 0; fm < 2; ++fm)
#pragma unroll
            for (int j = 0; j < 4; ++j) {
                float s = p_s[fm][j], q = p_q[fm][j];
                s += __shfl_xor(s, 1); s += __shfl_xor(s, 2); s += __shfl_xor(s, 4); s += __shfl_xor(s, 8);
                q += __shfl_xor(q, 1); q += __shfl_xor(q, 2); q += __shfl_xor(q, 4); q += __shfl_xor(q, 8);
                if (l15 == 0) {
                    int rr = fm * 16 + hi * 4 + j;
                    ps1[rr * 8 + w] = s; ps2[rr * 8 + w] = q;
                }
            }
    }
    __syncthreads();                                           // B2

    if (t < 32) {
        f32x4 a = *(f32x4*)&ps1[t * 8], bb = *(f32x4*)&ps1[t * 8 + 4];
        f32x4 cq = *(f32x4*)&ps2[t * 8], dq = *(f32x4*)&ps2[t * 8 + 4];
        float ts = a[0] + a[1] + a[2] + a[3] + bb[0] + bb[1] + bb[2] + bb[3];
        float tq = cq[0] + cq[1] + cq[2] + cq[3] + dq[0] + dq[1] + dq[2] + dq[3];
        float mu2 = ts * (1.f / 256.f);
        float var2 = tq * (1.f / 256.f) - mu2 * mu2;
        rmu2[t] = mu2; rrs2[t] = rsqrtf(var2 + 1e-5f);
    }

    // GEMM2
    f32x4 acc2[2][2];
#pragma unroll
    for (int fm = 0; fm < 2; ++fm)
#pragma unroll
        for (int fn = 0; fn < 2; ++fn) acc2[fm][fn] = (f32x4){0.f, 0.f, 0.f, 0.f};
#pragma unroll
    for (int kk = 0; kk < 8; ++kk) {
        bf16x8 a0 = *(const bf16x8*)&Hs[kk * 1280 + l15 * 40 + hi * 8];
        bf16x8 a1 = *(const bf16x8*)&Hs[kk * 1280 + (16 + l15) * 40 + hi * 8];
        acc2[0][0] = __builtin_amdgcn_mfma_f32_16x16x32_bf16(a0, bA[kk], acc2[0][0], 0, 0, 0);
        acc2[1][0] = __builtin_amdgcn_mfma_f32_16x16x32_bf16(a1, bA[kk], acc2[1][0], 0, 0, 0);
        acc2[0][1] = __builtin_amdgcn_mfma_f32_16x16x32_bf16(a0, bB[kk], acc2[0][1], 0, 0, 0);
        acc2[1][1] = __builtin_amdgcn_mfma_f32_16x16x32_bf16(a1, bB[kk], acc2[1][1], 0, 0, 0);
    }
    __syncthreads();                                           // B3

    // epilogue2: LN2-fold -> out
#pragma unroll
    for (int fn = 0; fn < 2; ++fn) {
        int colf = col0 + fn * 16 + l15;
        float vW2G = tb[TB_W2G * 256 + colf];
        float vB2  = tb[TB_B2  * 256 + colf];
#pragma unroll
        for (int fm = 0; fm < 2; ++fm)
#pragma unroll
            for (int j = 0; j < 4; ++j) {
                int rr = fm * 16 + hi * 4 + j;
                float o = rrs2[rr] * (acc2[fm][fn][j] - rmu2[rr] * vW2G) + vB2;
                out[(size_t)(r0 + rr) * 256 + colf] = o;
            }
    }
}

// ================================================================= launch
// DECOMPOSITION PROBE: k_main launched 3x (idempotent — reads prep outputs,
// writes only out). k_main_dur = (dur_r8 - dur_r7) / 2.
extern "C" void kernel_launch(void* const* d_in, const int* in_sizes, int n_in,
                              void* d_out, int out_size, void* d_ws, size_t ws_size,
                              hipStream_t stream) {
    const float* x   = (const float*)d_in[0];
    const float* fs  = (const float*)d_in[1];
    const float* ce  = (const float*)d_in[2];
    const float* se  = (const float*)d_in[3];
    const float* g1  = (const float*)d_in[4];
    const float* bb1 = (const float*)d_in[5];
    const float* W1  = (const float*)d_in[6];
    const float* b1  = (const float*)d_in[7];
    const float* g2  = (const float*)d_in[8];
    const float* bb2 = (const float*)d_in[9];
    const float* W2  = (const float*)d_in[10];
    const float* b2  = (const float*)d_in[11];
    const int* sL    = (const int*)d_in[12];
    const int* sC    = (const int*)d_in[13];
    const int* ctm   = (const int*)d_in[14];
    const int* sysid = (const int*)d_in[15];
    float* out = (float*)d_out;

    char* ws = (char*)d_ws;
    u16*   wdt  = (u16*)(ws + 0);          // 131072 B
    u16*   w2t  = (u16*)(ws + 131072);     // 131072 B
    float* tabF = (float*)(ws + 262144);   // 12288 B
    float* scal = (float*)(ws + 274432);   // 64 B

    k_zero<<<dim3(12), dim3(256), 0, stream>>>(tabF);
    k_prep<<<dim3(122), dim3(256), 0, stream>>>(
        W1, W2, g1, bb1, g2, bb2, ce, se, ctm, sysid, wdt, w2t, tabF, scal);
    k_main<<<dim3(NROWS / 32), dim3(512), 0, stream>>>(
        x, fs, sL, sC, wdt, w2t, tabF, scal, b1, b2, out);
    k_main<<<dim3(NROWS / 32), dim3(512), 0, stream>>>(
        x, fs, sL, sC, wdt, w2t, tabF, scal, b1, b2, out);
    k_main<<<dim3(NROWS / 32), dim3(512), 0, stream>>>(
        x, fs, sL, sC, wdt, w2t, tabF, scal, b1, b2, out);
}

// Round 9
// 52.983 us; speedup vs baseline: 1.6040x; 1.6040x over previous
//
#include <hip/hip_runtime.h>
#include <hip/hip_bf16.h>

typedef short bf16x8 __attribute__((ext_vector_type(8)));
typedef float f32x4 __attribute__((ext_vector_type(4)));
typedef unsigned short u16;

#define B_    32
#define L_    8192
#define C_    8
#define P_    512
#define D_    256
#define SED_  16
#define CED_  8
#define INDIM 2576
#define NROWS (B_ * P_)

#define TB_WTS 0
#define TB_IWT 1
#define TB_SYS 2
#define TB_GW1 3
#define TB_BWB 4
#define TB_CH0 5
#define TB_W2G 10
#define TB_B2  11

__device__ __forceinline__ u16 f2bf(float f) {
    __hip_bfloat16 h = __float2bfloat16(f);
    return *reinterpret_cast<u16*>(&h);
}

// ================================================================= zero tabF
__global__ __launch_bounds__(256) void k_zero(float* __restrict__ tabF) {
    tabF[blockIdx.x * 256 + threadIdx.x] = 0.f;
}

// ================================================================= prep
// blocks 0..80   : W1 fold partials -> atomicAdd tabF
// blocks 81..88  : W2 fold partials -> atomicAdd tabF
// blocks 89..120 : wdt fragment-order writer (g1*W1, data block k<256)
// blocks 121..152: w2t fragment-order writer (g2*W2)
// block  153     : scalar sums
// Fragment order: flat[((cg*8+kk)*64 + lane)*8 + e], col=cg*16+(lane&15),
// k = kk*32 + (lane>>4)*8 + e  -> a wave's load of 8 u16/lane is 1KB contiguous.
__global__ __launch_bounds__(256) void k_prep(
    const float* __restrict__ W1, const float* __restrict__ W2,
    const float* __restrict__ g1, const float* __restrict__ bb1,
    const float* __restrict__ g2, const float* __restrict__ bb2,
    const float* __restrict__ ce, const float* __restrict__ se,
    const int* __restrict__ ctm, const int* __restrict__ sysid,
    u16* __restrict__ wdt, u16* __restrict__ w2t,
    float* __restrict__ tabF, float* __restrict__ scal)
{
    __shared__ __attribute__((aligned(16))) char sh[8320];
    int c = blockIdx.x, n = threadIdx.x;

    if (c < 81) {
        float* sg = (float*)sh;
        float* sb = sg + 32;
        float* st = sb + 32;
        float (*cs5)[32] = (float(*)[32])(st + 32);
        int sid = sysid[0];
        int k0 = c * 32;
        int kend = INDIM - k0; if (kend > 32) kend = 32;
        int type = (k0 < 256) ? 0 : (k0 < 512) ? 1 : (k0 < 2560) ? 2 : 3;
        if (n < kend) {
            int k = k0 + n;
            sg[n] = g1[k]; sb[n] = bb1[k];
            float xv = 0.f;
            if (type == 1) xv = (float)((k - 256) >> 2);
            if (type == 3) xv = se[sid * SED_ + (k - 2560)];
            st[n] = xv;
        }
        if (type == 2 && n < 160) {
            int s = n >> 5, kt = n & 31, k = k0 + kt;
            cs5[s][kt] = ce[ctm[sid * 20 + s + ((k >> 3) & 3)] * CED_ + (k & 7)];
        }
        __syncthreads();
        float pg = 0, pb = 0, ai = 0, as_ = 0;
        float a5 = 0, a6 = 0, a7 = 0, a8 = 0, a9 = 0;
#pragma unroll 8
        for (int kt = 0; kt < kend; ++kt) {
            float wv = W1[(size_t)(k0 + kt) * D_ + n];
            float gw = sg[kt] * wv;
            pg += gw; pb += sb[kt] * wv;
            if (type == 1) ai += st[kt] * gw;
            if (type == 2) {
                a5 += cs5[0][kt] * gw; a6 += cs5[1][kt] * gw; a7 += cs5[2][kt] * gw;
                a8 += cs5[3][kt] * gw; a9 += cs5[4][kt] * gw;
            }
            if (type == 3) as_ += st[kt] * gw;
        }
        atomicAdd(&tabF[TB_GW1 * 256 + n], pg);
        atomicAdd(&tabF[TB_BWB * 256 + n], pb);
        if (type == 1) {
            atomicAdd(&tabF[TB_WTS * 256 + n], pg);
            atomicAdd(&tabF[TB_IWT * 256 + n], ai);
        }
        if (type == 2) {
            atomicAdd(&tabF[(TB_CH0 + 0) * 256 + n], a5);
            atomicAdd(&tabF[(TB_CH0 + 1) * 256 + n], a6);
            atomicAdd(&tabF[(TB_CH0 + 2) * 256 + n], a7);
            atomicAdd(&tabF[(TB_CH0 + 3) * 256 + n], a8);
            atomicAdd(&tabF[(TB_CH0 + 4) * 256 + n], a9);
        }
        if (type == 3) atomicAdd(&tabF[TB_SYS * 256 + n], as_);
    } else if (c < 89) {
        float* sg = (float*)sh;
        float* sb = sg + 32;
        int k0 = (c - 81) * 32;
        if (n < 32) { sg[n] = g2[k0 + n]; sb[n] = bb2[k0 + n]; }
        __syncthreads();
        float pg = 0, pb = 0;
#pragma unroll 8
        for (int kt = 0; kt < 32; ++kt) {
            float wv = W2[(size_t)(k0 + kt) * D_ + n];
            pg += sg[kt] * wv; pb += sb[kt] * wv;
        }
        atomicAdd(&tabF[TB_W2G * 256 + n], pg);
        atomicAdd(&tabF[TB_B2  * 256 + n], pb);
    } else if (c < 153) {
        // fragment-order weight writer
        int fb = c - 89;                 // 0..63
        const float* W = (fb < 32) ? W1 : W2;
        const float* g = (fb < 32) ? g1 : g2;
        u16* dst = (fb < 32) ? wdt : w2t;
        int cid = (fb & 31) * 256 + n;   // 0..8191 cell id
        int l = cid & 63;
        int col = ((cid >> 9) << 4) + (l & 15);          // cg*16 + l15
        int kb = (((cid >> 6) & 7) << 5) + ((l >> 4) << 3); // kk*32 + hi*8
        bf16x8 v;
#pragma unroll
        for (int e = 0; e < 8; ++e)
            v[e] = (short)f2bf(g[kb + e] * W[(size_t)(kb + e) * D_ + col]);
        *(bf16x8*)&dst[(size_t)cid * 8] = v;
    } else {
        float* sv = (float*)sh;
        float* sqv = sv + 176;
        int sid = sysid[0];
        if (n < 160) {
            int s5 = n >> 5, s = n & 31;
            float v = ce[ctm[sid * 20 + s5 + (s >> 3)] * CED_ + (s & 7)];
            sv[n] = v; sqv[n] = v * v;
        } else if (n < 176) {
            float v = se[sid * SED_ + (n - 160)];
            sv[n] = v; sqv[n] = v * v;
        }
        __syncthreads();
        if (n < 5) {
            float a = 0, bq = 0;
            for (int j2 = 0; j2 < 32; ++j2) { a += sv[n * 32 + j2]; bq += sqv[n * 32 + j2]; }
            scal[n] = a; scal[5 + n] = bq;
        }
        if (n == 10) {
            float a = 0, bq = 0;
            for (int j2 = 0; j2 < 16; ++j2) { a += sv[160 + j2]; bq += sqv[160 + j2]; }
            scal[10] = a; scal[11] = bq;
        }
        if (n >= 12 && n < 16) scal[n] = 0.f;
    }
}

// ================================================================= main fused
// 64 rows/block, 512 threads (8 waves = 2 row-halves x 4 col-groups),
// grid 256, XCD-bijective swizzle. H aliased onto As (barrier-protected).
// B-operands read in fragment order (fully coalesced, L2-hot).
__global__ __launch_bounds__(512, 4) void k_main(
    const float* __restrict__ x, const float* __restrict__ fs,
    const int* __restrict__ sLp, const int* __restrict__ sCp,
    const u16* __restrict__ wdt, const u16* __restrict__ w2t,
    const float* __restrict__ tabF, const float* __restrict__ scal,
    const float* __restrict__ b1, const float* __restrict__ b2,
    float* __restrict__ out)
{
    __shared__ __attribute__((aligned(16))) u16 As[8 * 64 * 40];   // 40 KB, chunk stride 2560
    __shared__ float tb[12 * 256];                                  // 12 KB
    __shared__ __attribute__((aligned(16))) float ps1[64 * 4], ps2[64 * 4];
    __shared__ float rmu[64], rrs[64], rsl[64];
    __shared__ int   rsc[64];
    __shared__ float rmu2[64], rrs2[64];

    int t = threadIdx.x;
    int tile = ((blockIdx.x & 7) << 5) + (blockIdx.x >> 3);   // 8x32 bijective
    int r0 = tile * 64;
    int b = tile >> 3;
    float fsinv = 1.0f / fs[b];

    int row = t >> 3, u = t & 7;
    int lane = t & 63, l15 = lane & 15, hi = lane >> 4;
    int w = t >> 6, wr = w >> 2, wc = w & 3;

    int r = r0 + row;
    int sL = sLp[r], sC = sCp[r];

    // tb staging (b1/b2 folded by the staging thread)
    for (int i = t; i < 12 * 256; i += 512) tb[i] = tabF[i];
    if (t < 256) tb[TB_BWB * 256 + t] += b1[t];
    else         tb[TB_B2  * 256 + (t - 256)] += b2[t - 256];

    // ---- gather + LN1 stats (8 threads/row, shfl reduce)
    {
        const float* xb = x + ((size_t)b << 16);
        float s = 0.f, sq = 0.f;
#pragma unroll
        for (int i2 = 0; i2 < 8; ++i2) {
            int i = i2 * 8 + u;
            const float* px = xb + (size_t)(sL + i) * 8 + sC;
            f32x4 v;
            __builtin_memcpy(&v, px, 16);
            s += v[0] + v[1] + v[2] + v[3];
            sq += v[0] * v[0] + v[1] * v[1] + v[2] * v[2] + v[3] * v[3];
            *(ushort4*)&As[i2 * 2560 + row * 40 + u * 4] =
                make_ushort4(f2bf(v[0]), f2bf(v[1]), f2bf(v[2]), f2bf(v[3]));
        }
        s += __shfl_xor(s, 1); s += __shfl_xor(s, 2); s += __shfl_xor(s, 4);
        sq += __shfl_xor(sq, 1); sq += __shfl_xor(sq, 2); sq += __shfl_xor(sq, 4);
        if (u == 0) {
            float sLf = (float)sL;
            float Ss = s + 4.f * fsinv * (64.f * sLf + 2016.f) + 64.f * scal[sC] + scal[10];
            float Sq = sq + 4.f * fsinv * fsinv * (64.f * sLf * sLf + 4032.f * sLf + 85344.f)
                     + 64.f * scal[5 + sC] + scal[11];
            float mu = Ss * (1.f / (float)INDIM);
            float var = Sq * (1.f / (float)INDIM) - mu * mu;
            rmu[row] = mu; rrs[row] = rsqrtf(var + 1e-5f);
            rsl[row] = sLf; rsc[row] = sC;
        }
    }
    __syncthreads();                                           // B1

    // ---- GEMM1 (K=256): LDS-A + coalesced fragment B (L2-hot)
    f32x4 acc[2][4];
#pragma unroll
    for (int fm = 0; fm < 2; ++fm)
#pragma unroll
        for (int fn = 0; fn < 4; ++fn) acc[fm][fn] = (f32x4){0.f, 0.f, 0.f, 0.f};
#pragma unroll
    for (int kk = 0; kk < 8; ++kk) {
        bf16x8 a0 = *(const bf16x8*)&As[kk * 2560 + (wr * 32 + l15) * 40 + hi * 8];
        bf16x8 a1 = *(const bf16x8*)&As[kk * 2560 + (wr * 32 + 16 + l15) * 40 + hi * 8];
#pragma unroll
        for (int fn = 0; fn < 4; ++fn) {
            int cg = wc * 4 + fn;
            bf16x8 bv = *(const bf16x8*)&wdt[(size_t)(((cg * 8 + kk) * 64 + lane)) * 8];
            acc[0][fn] = __builtin_amdgcn_mfma_f32_16x16x32_bf16(a0, bv, acc[0][fn], 0, 0, 0);
            acc[1][fn] = __builtin_amdgcn_mfma_f32_16x16x32_bf16(a1, bv, acc[1][fn], 0, 0, 0);
        }
    }
    __syncthreads();                                           // B1.5: As reads done

    // ---- epilogue1: LN1-fold + SiLU -> H (into As), LN2 partials
    {
        float p_s[2][4] = {}, p_q[2][4] = {};
#pragma unroll
        for (int fn = 0; fn < 4; ++fn) {
            int colf = wc * 64 + fn * 16 + l15;
            float vwts = tb[TB_WTS * 256 + colf];
            float viwt = tb[TB_IWT * 256 + colf];
            float vsys = tb[TB_SYS * 256 + colf];
            float vgw1 = tb[TB_GW1 * 256 + colf];
            float vbwb = tb[TB_BWB * 256 + colf];
            const float* tch = &tb[TB_CH0 * 256 + colf];
#pragma unroll
            for (int fm = 0; fm < 2; ++fm)
#pragma unroll
                for (int j = 0; j < 4; ++j) {
                    int rr = wr * 32 + fm * 16 + hi * 4 + j;
                    float fw = acc[fm][fn][j]
                             + fsinv * (rsl[rr] * vwts + viwt)
                             + tch[rsc[rr] * 256] + vsys;
                    float o1 = rrs[rr] * (fw - rmu[rr] * vgw1) + vbwb;
                    float h = o1 / (1.f + __expf(-o1));
                    p_s[fm][j] += h; p_q[fm][j] += h * h;
                    As[(colf >> 5) * 2560 + rr * 40 + (colf & 31)] = f2bf(h);
                }
        }
#pragma unroll
        for (int fm = 0; fm < 2; ++fm)
#pragma unroll
            for (int j = 0; j < 4; ++j) {
                float s = p_s[fm][j], q = p_q[fm][j];
                s += __shfl_xor(s, 1); s += __shfl_xor(s, 2); s += __shfl_xor(s, 4); s += __shfl_xor(s, 8);
                q += __shfl_xor(q, 1); q += __shfl_xor(q, 2); q += __shfl_xor(q, 4); q += __shfl_xor(q, 8);
                if (l15 == 0) {
                    int rr = wr * 32 + fm * 16 + hi * 4 + j;
                    ps1[rr * 4 + wc] = s; ps2[rr * 4 + wc] = q;
                }
            }
    }
    __syncthreads();                                           // B2

    // ---- stats2 (t<64) overlapped with GEMM2
    if (t < 64) {
        f32x4 a = *(f32x4*)&ps1[t * 4];
        f32x4 cq = *(f32x4*)&ps2[t * 4];
        float ts = a[0] + a[1] + a[2] + a[3];
        float tq = cq[0] + cq[1] + cq[2] + cq[3];
        float mu2 = ts * (1.f / 256.f);
        float var2 = tq * (1.f / 256.f) - mu2 * mu2;
        rmu2[t] = mu2; rrs2[t] = rsqrtf(var2 + 1e-5f);
    }

    // ---- GEMM2 (K=256): H from As + coalesced fragment w2t
    f32x4 acc2[2][4];
#pragma unroll
    for (int fm = 0; fm < 2; ++fm)
#pragma unroll
        for (int fn = 0; fn < 4; ++fn) acc2[fm][fn] = (f32x4){0.f, 0.f, 0.f, 0.f};
#pragma unroll
    for (int kk = 0; kk < 8; ++kk) {
        bf16x8 a0 = *(const bf16x8*)&As[kk * 2560 + (wr * 32 + l15) * 40 + hi * 8];
        bf16x8 a1 = *(const bf16x8*)&As[kk * 2560 + (wr * 32 + 16 + l15) * 40 + hi * 8];
#pragma unroll
        for (int fn = 0; fn < 4; ++fn) {
            int cg = wc * 4 + fn;
            bf16x8 bv = *(const bf16x8*)&w2t[(size_t)(((cg * 8 + kk) * 64 + lane)) * 8];
            acc2[0][fn] = __builtin_amdgcn_mfma_f32_16x16x32_bf16(a0, bv, acc2[0][fn], 0, 0, 0);
            acc2[1][fn] = __builtin_amdgcn_mfma_f32_16x16x32_bf16(a1, bv, acc2[1][fn], 0, 0, 0);
        }
    }
    __syncthreads();                                           // B3: stats2 visible

    // ---- epilogue2: LN2-fold -> out
#pragma unroll
    for (int fn = 0; fn < 4; ++fn) {
        int colf = wc * 64 + fn * 16 + l15;
        float vW2G = tb[TB_W2G * 256 + colf];
        float vB2  = tb[TB_B2  * 256 + colf];
#pragma unroll
        for (int fm = 0; fm < 2; ++fm)
#pragma unroll
            for (int j = 0; j < 4; ++j) {
                int rr = wr * 32 + fm * 16 + hi * 4 + j;
                float o = rrs2[rr] * (acc2[fm][fn][j] - rmu2[rr] * vW2G) + vB2;
                out[(size_t)(r0 + rr) * 256 + colf] = o;
            }
    }
}

// ================================================================= launch
extern "C" void kernel_launch(void* const* d_in, const int* in_sizes, int n_in,
                              void* d_out, int out_size, void* d_ws, size_t ws_size,
                              hipStream_t stream) {
    const float* x   = (const float*)d_in[0];
    const float* fs  = (const float*)d_in[1];
    const float* ce  = (const float*)d_in[2];
    const float* se  = (const float*)d_in[3];
    const float* g1  = (const float*)d_in[4];
    const float* bb1 = (const float*)d_in[5];
    const float* W1  = (const float*)d_in[6];
    const float* b1  = (const float*)d_in[7];
    const float* g2  = (const float*)d_in[8];
    const float* bb2 = (const float*)d_in[9];
    const float* W2  = (const float*)d_in[10];
    const float* b2  = (const float*)d_in[11];
    const int* sL    = (const int*)d_in[12];
    const int* sC    = (const int*)d_in[13];
    const int* ctm   = (const int*)d_in[14];
    const int* sysid = (const int*)d_in[15];
    float* out = (float*)d_out;

    char* ws = (char*)d_ws;
    u16*   wdt  = (u16*)(ws + 0);          // 131072 B (fragment order)
    u16*   w2t  = (u16*)(ws + 131072);     // 131072 B (fragment order)
    float* tabF = (float*)(ws + 262144);   // 12288 B
    float* scal = (float*)(ws + 274432);   // 64 B

    k_zero<<<dim3(12), dim3(256), 0, stream>>>(tabF);
    k_prep<<<dim3(154), dim3(256), 0, stream>>>(
        W1, W2, g1, bb1, g2, bb2, ce, se, ctm, sysid, wdt, w2t, tabF, scal);
    k_main<<<dim3(NROWS / 64), dim3(512), 0, stream>>>(
        x, fs, sL, sC, wdt, w2t, tabF, scal, b1, b2, out);
}

// Round 10
// 39.968 us; speedup vs baseline: 2.1264x; 1.3256x over previous
//
#include <hip/hip_runtime.h>
#include <hip/hip_bf16.h>

typedef short bf16x8 __attribute__((ext_vector_type(8)));
typedef float f32x4 __attribute__((ext_vector_type(4)));
typedef unsigned short u16;

#define B_    32
#define L_    8192
#define C_    8
#define P_    512
#define D_    256
#define SED_  16
#define CED_  8
#define INDIM 2576
#define NROWS (B_ * P_)

#define TB_WTS 0
#define TB_IWT 1
#define TB_SYS 2
#define TB_GW1 3
#define TB_BWB 4
#define TB_CH0 5
#define TB_W2G 10
#define TB_B2  11

__device__ __forceinline__ u16 f2bf(float f) {
    __hip_bfloat16 h = __float2bfloat16(f);
    return *reinterpret_cast<u16*>(&h);
}

// ================================================================= zero tabF
__global__ __launch_bounds__(256) void k_zero(float* __restrict__ tabF) {
    tabF[blockIdx.x * 256 + threadIdx.x] = 0.f;
}

// ================================================================= prep (r9 version — verified)
__global__ __launch_bounds__(256) void k_prep(
    const float* __restrict__ W1, const float* __restrict__ W2,
    const float* __restrict__ g1, const float* __restrict__ bb1,
    const float* __restrict__ g2, const float* __restrict__ bb2,
    const float* __restrict__ ce, const float* __restrict__ se,
    const int* __restrict__ ctm, const int* __restrict__ sysid,
    u16* __restrict__ wdt, u16* __restrict__ w2t,
    float* __restrict__ tabF, float* __restrict__ scal)
{
    __shared__ __attribute__((aligned(16))) char sh[8320];
    int c = blockIdx.x, n = threadIdx.x;

    if (c < 81) {
        float* sg = (float*)sh;
        float* sb = sg + 32;
        float* st = sb + 32;
        float (*cs5)[32] = (float(*)[32])(st + 32);
        int sid = sysid[0];
        int k0 = c * 32;
        int kend = INDIM - k0; if (kend > 32) kend = 32;
        int type = (k0 < 256) ? 0 : (k0 < 512) ? 1 : (k0 < 2560) ? 2 : 3;
        if (n < kend) {
            int k = k0 + n;
            sg[n] = g1[k]; sb[n] = bb1[k];
            float xv = 0.f;
            if (type == 1) xv = (float)((k - 256) >> 2);
            if (type == 3) xv = se[sid * SED_ + (k - 2560)];
            st[n] = xv;
        }
        if (type == 2 && n < 160) {
            int s = n >> 5, kt = n & 31, k = k0 + kt;
            cs5[s][kt] = ce[ctm[sid * 20 + s + ((k >> 3) & 3)] * CED_ + (k & 7)];
        }
        __syncthreads();
        float pg = 0, pb = 0, ai = 0, as_ = 0;
        float a5 = 0, a6 = 0, a7 = 0, a8 = 0, a9 = 0;
#pragma unroll 8
        for (int kt = 0; kt < kend; ++kt) {
            float wv = W1[(size_t)(k0 + kt) * D_ + n];
            float gw = sg[kt] * wv;
            pg += gw; pb += sb[kt] * wv;
            if (type == 1) ai += st[kt] * gw;
            if (type == 2) {
                a5 += cs5[0][kt] * gw; a6 += cs5[1][kt] * gw; a7 += cs5[2][kt] * gw;
                a8 += cs5[3][kt] * gw; a9 += cs5[4][kt] * gw;
            }
            if (type == 3) as_ += st[kt] * gw;
        }
        atomicAdd(&tabF[TB_GW1 * 256 + n], pg);
        atomicAdd(&tabF[TB_BWB * 256 + n], pb);
        if (type == 1) {
            atomicAdd(&tabF[TB_WTS * 256 + n], pg);
            atomicAdd(&tabF[TB_IWT * 256 + n], ai);
        }
        if (type == 2) {
            atomicAdd(&tabF[(TB_CH0 + 0) * 256 + n], a5);
            atomicAdd(&tabF[(TB_CH0 + 1) * 256 + n], a6);
            atomicAdd(&tabF[(TB_CH0 + 2) * 256 + n], a7);
            atomicAdd(&tabF[(TB_CH0 + 3) * 256 + n], a8);
            atomicAdd(&tabF[(TB_CH0 + 4) * 256 + n], a9);
        }
        if (type == 3) atomicAdd(&tabF[TB_SYS * 256 + n], as_);
    } else if (c < 89) {
        float* sg = (float*)sh;
        float* sb = sg + 32;
        int k0 = (c - 81) * 32;
        if (n < 32) { sg[n] = g2[k0 + n]; sb[n] = bb2[k0 + n]; }
        __syncthreads();
        float pg = 0, pb = 0;
#pragma unroll 8
        for (int kt = 0; kt < 32; ++kt) {
            float wv = W2[(size_t)(k0 + kt) * D_ + n];
            pg += sg[kt] * wv; pb += sb[kt] * wv;
        }
        atomicAdd(&tabF[TB_W2G * 256 + n], pg);
        atomicAdd(&tabF[TB_B2  * 256 + n], pb);
    } else if (c < 153) {
        // fragment-order weight writer: flat[((cg*8+kk)*64+lane)*8+e]
        int fb = c - 89;                 // 0..63
        const float* W = (fb < 32) ? W1 : W2;
        const float* g = (fb < 32) ? g1 : g2;
        u16* dst = (fb < 32) ? wdt : w2t;
        int cid = (fb & 31) * 256 + n;
        int l = cid & 63;
        int col = ((cid >> 9) << 4) + (l & 15);
        int kb = (((cid >> 6) & 7) << 5) + ((l >> 4) << 3);
        bf16x8 v;
#pragma unroll
        for (int e = 0; e < 8; ++e)
            v[e] = (short)f2bf(g[kb + e] * W[(size_t)(kb + e) * D_ + col]);
        *(bf16x8*)&dst[(size_t)cid * 8] = v;
    } else {
        float* sv = (float*)sh;
        float* sqv = sv + 176;
        int sid = sysid[0];
        if (n < 160) {
            int s5 = n >> 5, s = n & 31;
            float v = ce[ctm[sid * 20 + s5 + (s >> 3)] * CED_ + (s & 7)];
            sv[n] = v; sqv[n] = v * v;
        } else if (n < 176) {
            float v = se[sid * SED_ + (n - 160)];
            sv[n] = v; sqv[n] = v * v;
        }
        __syncthreads();
        if (n < 5) {
            float a = 0, bq = 0;
            for (int j2 = 0; j2 < 32; ++j2) { a += sv[n * 32 + j2]; bq += sqv[n * 32 + j2]; }
            scal[n] = a; scal[5 + n] = bq;
        }
        if (n == 10) {
            float a = 0, bq = 0;
            for (int j2 = 0; j2 < 16; ++j2) { a += sv[160 + j2]; bq += sqv[160 + j2]; }
            scal[10] = a; scal[11] = bq;
        }
        if (n >= 12 && n < 16) scal[n] = 0.f;
    }
}

// ================================================================= main fused
// M=32, 512 threads, grid 512 (2 blocks/CU). B preloaded to regs from
// fragment-order weights (coalesced). No LDS table staging — epilogue tables
// read direct from L2 after GEMM1. 3 barriers.
__global__ __launch_bounds__(512, 4) void k_main(
    const float* __restrict__ x, const float* __restrict__ fs,
    const int* __restrict__ sLp, const int* __restrict__ sCp,
    const u16* __restrict__ wdt, const u16* __restrict__ w2t,
    const float* __restrict__ tabF, const float* __restrict__ scal,
    const float* __restrict__ b1, const float* __restrict__ b2,
    float* __restrict__ out)
{
    __shared__ __attribute__((aligned(16))) u16 As[8 * 32 * 40];  // 20.5 KB
    __shared__ __attribute__((aligned(16))) u16 Hs[8 * 32 * 40];  // 20.5 KB
    __shared__ __attribute__((aligned(16))) float ps1[32 * 8], ps2[32 * 8];
    __shared__ float rmu[32], rrs[32], rsl[32];
    __shared__ int   rsc[32];
    __shared__ float rmu2[32], rrs2[32];

    int t = threadIdx.x;
    int tile = ((blockIdx.x & 7) << 6) + (blockIdx.x >> 3);   // XCD-bijective
    int r0 = tile * 32;
    int b = r0 >> 9;
    float fsinv = 1.0f / fs[b];

    int row = t >> 4, u = t & 15;
    int w = t >> 6, lane = t & 63, l15 = lane & 15, hi = lane >> 4;
    int col0 = w * 32;

    int r = r0 + row;
    int sL = sLp[r], sC = sCp[r];

    // GEMM1 B preload: 16 independent coalesced loads (1 KB/wave each),
    // issued before the gather so the latencies overlap.
    bf16x8 bA[8], bB[8];
    {
        const u16* p0 = &wdt[(size_t)(((2 * w) * 8) * 64 + lane) * 8];
        const u16* p1 = &wdt[(size_t)(((2 * w + 1) * 8) * 64 + lane) * 8];
#pragma unroll
        for (int kk = 0; kk < 8; ++kk) {
            bA[kk] = *(const bf16x8*)(p0 + (size_t)kk * 512);
            bB[kk] = *(const bf16x8*)(p1 + (size_t)kk * 512);
        }
    }

    // ---- gather + LN1 stats (16 threads/row, shfl reduce)
    {
        const float* xb = x + ((size_t)b << 16);
        float s = 0.f, sq = 0.f;
#pragma unroll
        for (int i2 = 0; i2 < 4; ++i2) {
            int i = i2 * 16 + u;
            const float* px = xb + (size_t)(sL + i) * 8 + sC;
            f32x4 v;
            __builtin_memcpy(&v, px, 16);
            s += v[0] + v[1] + v[2] + v[3];
            sq += v[0] * v[0] + v[1] * v[1] + v[2] * v[2] + v[3] * v[3];
            *(ushort4*)&As[(i2 * 2 + (u >> 3)) * 1280 + row * 40 + (u & 7) * 4] =
                make_ushort4(f2bf(v[0]), f2bf(v[1]), f2bf(v[2]), f2bf(v[3]));
        }
        s += __shfl_xor(s, 1); s += __shfl_xor(s, 2); s += __shfl_xor(s, 4); s += __shfl_xor(s, 8);
        sq += __shfl_xor(sq, 1); sq += __shfl_xor(sq, 2); sq += __shfl_xor(sq, 4); sq += __shfl_xor(sq, 8);
        if (u == 0) {
            float sLf = (float)sL;
            float Ss = s + 4.f * fsinv * (64.f * sLf + 2016.f) + 64.f * scal[sC] + scal[10];
            float Sq = sq + 4.f * fsinv * fsinv * (64.f * sLf * sLf + 4032.f * sLf + 85344.f)
                     + 64.f * scal[5 + sC] + scal[11];
            float mu = Ss * (1.f / (float)INDIM);
            float var = Sq * (1.f / (float)INDIM) - mu * mu;
            rmu[row] = mu; rrs[row] = rsqrtf(var + 1e-5f);
            rsl[row] = sLf; rsc[row] = sC;
        }
    }
    __syncthreads();                                           // B1

    // ---- GEMM1 (K=256): LDS-A + in-reg B
    f32x4 acc[2][2];
#pragma unroll
    for (int fm = 0; fm < 2; ++fm)
#pragma unroll
        for (int fn = 0; fn < 2; ++fn) acc[fm][fn] = (f32x4){0.f, 0.f, 0.f, 0.f};
#pragma unroll
    for (int kk = 0; kk < 8; ++kk) {
        bf16x8 a0 = *(const bf16x8*)&As[kk * 1280 + l15 * 40 + hi * 8];
        bf16x8 a1 = *(const bf16x8*)&As[kk * 1280 + (16 + l15) * 40 + hi * 8];
        acc[0][0] = __builtin_amdgcn_mfma_f32_16x16x32_bf16(a0, bA[kk], acc[0][0], 0, 0, 0);
        acc[1][0] = __builtin_amdgcn_mfma_f32_16x16x32_bf16(a1, bA[kk], acc[1][0], 0, 0, 0);
        acc[0][1] = __builtin_amdgcn_mfma_f32_16x16x32_bf16(a0, bB[kk], acc[0][1], 0, 0, 0);
        acc[1][1] = __builtin_amdgcn_mfma_f32_16x16x32_bf16(a1, bB[kk], acc[1][1], 0, 0, 0);
    }

    // ---- GEMM2 B preload (lands under epilogue-1 VALU)
    {
        const u16* p0 = &w2t[(size_t)(((2 * w) * 8) * 64 + lane) * 8];
        const u16* p1 = &w2t[(size_t)(((2 * w + 1) * 8) * 64 + lane) * 8];
#pragma unroll
        for (int kk = 0; kk < 8; ++kk) {
            bA[kk] = *(const bf16x8*)(p0 + (size_t)kk * 512);
            bB[kk] = *(const bf16x8*)(p1 + (size_t)kk * 512);
        }
    }

    // ---- epilogue1: LN1-fold + SiLU -> Hs, LN2 partials; tables from L2
    {
        float p_s[2][4] = {}, p_q[2][4] = {};
#pragma unroll
        for (int fn = 0; fn < 2; ++fn) {
            int colf = col0 + fn * 16 + l15;
            float vwts = tabF[TB_WTS * 256 + colf];
            float viwt = tabF[TB_IWT * 256 + colf];
            float vsys = tabF[TB_SYS * 256 + colf];
            float vgw1 = tabF[TB_GW1 * 256 + colf];
            float vbwb = tabF[TB_BWB * 256 + colf] + b1[colf];
            const float* tch = &tabF[TB_CH0 * 256 + colf];
#pragma unroll
            for (int fm = 0; fm < 2; ++fm)
#pragma unroll
                for (int j = 0; j < 4; ++j) {
                    int rr = fm * 16 + hi * 4 + j;
                    float fw = acc[fm][fn][j]
                             + fsinv * (rsl[rr] * vwts + viwt)
                             + tch[rsc[rr] * 256] + vsys;
                    float o1 = rrs[rr] * (fw - rmu[rr] * vgw1) + vbwb;
                    float h = o1 / (1.f + __expf(-o1));
                    p_s[fm][j] += h; p_q[fm][j] += h * h;
                    Hs[w * 1280 + rr * 40 + fn * 16 + l15] = f2bf(h);
                }
        }
#pragma unroll
        for (int fm = 0; fm < 2; ++fm)
#pragma unroll
            for (int j = 0; j < 4; ++j) {
                float s = p_s[fm][j], q = p_q[fm][j];
                s += __shfl_xor(s, 1); s += __shfl_xor(s, 2); s += __shfl_xor(s, 4); s += __shfl_xor(s, 8);
                q += __shfl_xor(q, 1); q += __shfl_xor(q, 2); q += __shfl_xor(q, 4); q += __shfl_xor(q, 8);
                if (l15 == 0) {
                    int rr = fm * 16 + hi * 4 + j;
                    ps1[rr * 8 + w] = s; ps2[rr * 8 + w] = q;
                }
            }
    }
    __syncthreads();                                           // B2

    // ---- stats2 (t<32) overlapped with GEMM2
    if (t < 32) {
        f32x4 a = *(f32x4*)&ps1[t * 8], bb = *(f32x4*)&ps1[t * 8 + 4];
        f32x4 cq = *(f32x4*)&ps2[t * 8], dq = *(f32x4*)&ps2[t * 8 + 4];
        float ts = a[0] + a[1] + a[2] + a[3] + bb[0] + bb[1] + bb[2] + bb[3];
        float tq = cq[0] + cq[1] + cq[2] + cq[3] + dq[0] + dq[1] + dq[2] + dq[3];
        float mu2 = ts * (1.f / 256.f);
        float var2 = tq * (1.f / 256.f) - mu2 * mu2;
        rmu2[t] = mu2; rrs2[t] = rsqrtf(var2 + 1e-5f);
    }

    // ---- GEMM2 (K=256): LDS-Hs + in-reg B
    f32x4 acc2[2][2];
#pragma unroll
    for (int fm = 0; fm < 2; ++fm)
#pragma unroll
        for (int fn = 0; fn < 2; ++fn) acc2[fm][fn] = (f32x4){0.f, 0.f, 0.f, 0.f};
#pragma unroll
    for (int kk = 0; kk < 8; ++kk) {
        bf16x8 a0 = *(const bf16x8*)&Hs[kk * 1280 + l15 * 40 + hi * 8];
        bf16x8 a1 = *(const bf16x8*)&Hs[kk * 1280 + (16 + l15) * 40 + hi * 8];
        acc2[0][0] = __builtin_amdgcn_mfma_f32_16x16x32_bf16(a0, bA[kk], acc2[0][0], 0, 0, 0);
        acc2[1][0] = __builtin_amdgcn_mfma_f32_16x16x32_bf16(a1, bA[kk], acc2[1][0], 0, 0, 0);
        acc2[0][1] = __builtin_amdgcn_mfma_f32_16x16x32_bf16(a0, bB[kk], acc2[0][1], 0, 0, 0);
        acc2[1][1] = __builtin_amdgcn_mfma_f32_16x16x32_bf16(a1, bB[kk], acc2[1][1], 0, 0, 0);
    }
    __syncthreads();                                           // B3

    // ---- epilogue2: LN2-fold -> out (tables from L2, issued during GEMM2)
#pragma unroll
    for (int fn = 0; fn < 2; ++fn) {
        int colf = col0 + fn * 16 + l15;
        float vW2G = tabF[TB_W2G * 256 + colf];
        float vB2  = tabF[TB_B2  * 256 + colf] + b2[colf];
#pragma unroll
        for (int fm = 0; fm < 2; ++fm)
#pragma unroll
            for (int j = 0; j < 4; ++j) {
                int rr = fm * 16 + hi * 4 + j;
                float o = rrs2[rr] * (acc2[fm][fn][j] - rmu2[rr] * vW2G) + vB2;
                out[(size_t)(r0 + rr) * 256 + colf] = o;
            }
    }
}

// ================================================================= launch
extern "C" void kernel_launch(void* const* d_in, const int* in_sizes, int n_in,
                              void* d_out, int out_size, void* d_ws, size_t ws_size,
                              hipStream_t stream) {
    const float* x   = (const float*)d_in[0];
    const float* fs  = (const float*)d_in[1];
    const float* ce  = (const float*)d_in[2];
    const float* se  = (const float*)d_in[3];
    const float* g1  = (const float*)d_in[4];
    const float* bb1 = (const float*)d_in[5];
    const float* W1  = (const float*)d_in[6];
    const float* b1  = (const float*)d_in[7];
    const float* g2  = (const float*)d_in[8];
    const float* bb2 = (const float*)d_in[9];
    const float* W2  = (const float*)d_in[10];
    const float* b2  = (const float*)d_in[11];
    const int* sL    = (const int*)d_in[12];
    const int* sC    = (const int*)d_in[13];
    const int* ctm   = (const int*)d_in[14];
    const int* sysid = (const int*)d_in[15];
    float* out = (float*)d_out;

    char* ws = (char*)d_ws;
    u16*   wdt  = (u16*)(ws + 0);          // 131072 B (fragment order)
    u16*   w2t  = (u16*)(ws + 131072);     // 131072 B (fragment order)
    float* tabF = (float*)(ws + 262144);   // 12288 B
    float* scal = (float*)(ws + 274432);   // 64 B

    k_zero<<<dim3(12), dim3(256), 0, stream>>>(tabF);
    k_prep<<<dim3(154), dim3(256), 0, stream>>>(
        W1, W2, g1, bb1, g2, bb2, ce, se, ctm, sysid, wdt, w2t, tabF, scal);
    k_main<<<dim3(NROWS / 32), dim3(512), 0, stream>>>(
        x, fs, sL, sC, wdt, w2t, tabF, scal, b1, b2, out);
}